// Round 1
// baseline (349.250 us; speedup 1.0000x reference)
//
#include <hip/hip_runtime.h>
#include <hip/hip_bf16.h>
#include <math.h>

// Problem constants (fixed by the reference)
#define NROWS   65536          // 16*4096 flattened rows
#define DIM     64             // embedding dim
#define KCODES  1024           // num embeddings
#define KCHUNK  128            // codes staged in LDS per iteration
#define NCHUNKS (KCODES / KCHUNK)

// Output layout (floats), concatenated in reference return order:
//   out[0]                               loss
//   out[1 .. 1+NROWS*DIM-1]              quantized_ste  (== wn[idx] numerically)
//   out[1+NROWS*DIM]                     perplexity
//   out[2+NROWS*DIM .. ]                 encoding_indices (written as float)
#define OUT_Q_OFF    ((size_t)1)
#define OUT_PERP_OFF ((size_t)(1 + (size_t)NROWS * DIM))
#define OUT_IDX_OFF  ((size_t)(2 + (size_t)NROWS * DIM))

// Workspace layout (bytes):
//   [0,      4096)   unsigned counts[1024]     (zeroed each call)
//   [4096,   5120)   float block_sse[256]      (zeroed each call)
//   [5120, 267264)   float wn[65536]           (normalized codebook)
//   [267264,271360)  float sk[1024]            (sum(wn^2) per code)

__global__ void __launch_bounds__(64) normalize_w_kernel(
    const float* __restrict__ w, float* __restrict__ wn, float* __restrict__ sk) {
  const int k = blockIdx.x;   // one code per 64-lane wave
  const int d = threadIdx.x;
  float v = w[k * DIM + d];
  float ss = v * v;
  #pragma unroll
  for (int o = 32; o > 0; o >>= 1) ss += __shfl_xor(ss, o, 64);
  const float den = fmaxf(sqrtf(ss), 1e-12f);   // torch/jax F.normalize eps
  const float q = v / den;                      // true division to hug reference rounding
  wn[k * DIM + d] = q;
  float s2 = q * q;
  #pragma unroll
  for (int o = 32; o > 0; o >>= 1) s2 += __shfl_xor(s2, o, 64);
  if (d == 0) sk[k] = s2;
}

__global__ void __launch_bounds__(256) vq_main_kernel(
    const float* __restrict__ x, const float* __restrict__ wn,
    const float* __restrict__ sk, float* __restrict__ out,
    unsigned* __restrict__ counts, float* __restrict__ block_sse) {
  __shared__ float4 wlds[KCHUNK * 16];   // 128 codes x 64 floats = 32 KB
  __shared__ float  sklds[KCHUNK];
  __shared__ float  red[256];
  __shared__ int    ib[256];

  const int tid = threadIdx.x;
  const size_t r = (size_t)blockIdx.x * 256 + tid;   // one row per thread

  // ---- load + L2-normalize this thread's row into registers (64 VGPRs) ----
  float4 xv[16];
  const float4* xrow = (const float4*)(x + r * DIM);
  #pragma unroll
  for (int i = 0; i < 16; i++) xv[i] = xrow[i];
  float ss = 0.f;
  #pragma unroll
  for (int i = 0; i < 16; i++)
    ss += xv[i].x * xv[i].x + xv[i].y * xv[i].y + xv[i].z * xv[i].z + xv[i].w * xv[i].w;
  const float den = fmaxf(sqrtf(ss), 1e-12f);
  #pragma unroll
  for (int i = 0; i < 16; i++) {
    xv[i].x /= den; xv[i].y /= den; xv[i].z /= den; xv[i].w /= den;
  }
  // c = sum(xn^2), kept to mirror reference rounding of (c + sk) - 2*dot
  float c = 0.f;
  #pragma unroll
  for (int i = 0; i < 16; i++)
    c += xv[i].x * xv[i].x + xv[i].y * xv[i].y + xv[i].z * xv[i].z + xv[i].w * xv[i].w;

  float best = INFINITY;
  int bidx = 0;

  for (int ch = 0; ch < NCHUNKS; ch++) {
    const int c0 = ch * KCHUNK;
    __syncthreads();  // guard LDS reuse from previous chunk
    // cooperative coalesced stage: 8192 floats = 2048 float4 / 256 threads
    const float4* src = (const float4*)(wn + (size_t)c0 * DIM);
    #pragma unroll
    for (int j = 0; j < 8; j++) wlds[j * 256 + tid] = src[j * 256 + tid];
    if (tid < KCHUNK) sklds[tid] = sk[c0 + tid];
    __syncthreads();

    // wave-uniform broadcast reads of w; 4 independent FMA chains for ILP
    for (int kk = 0; kk < KCHUNK; kk++) {
      const float4* wr = &wlds[kk * 16];
      float d0 = 0.f, d1 = 0.f, d2 = 0.f, d3 = 0.f;
      #pragma unroll
      for (int i = 0; i < 16; i++) {
        float4 wv = wr[i];
        d0 = fmaf(xv[i].x, wv.x, d0);
        d1 = fmaf(xv[i].y, wv.y, d1);
        d2 = fmaf(xv[i].z, wv.z, d2);
        d3 = fmaf(xv[i].w, wv.w, d3);
      }
      const float dot = (d0 + d1) + (d2 + d3);
      const float dist = (c + sklds[kk]) - 2.0f * dot;
      if (dist < best) { best = dist; bidx = c0 + kk; }  // strict <: first-min, matches jnp.argmin
    }
  }

  // ---- epilogue ----
  out[OUT_IDX_OFF + r] = (float)bidx;
  atomicAdd(&counts[bidx], 1u);

  // SSE contribution of this row: sum((wn[bidx] - xn)^2)
  float sse = 0.f;
  const float4* qrow = (const float4*)(wn + (size_t)bidx * DIM);
  #pragma unroll
  for (int i = 0; i < 16; i++) {
    float4 q = qrow[i];
    float e0 = q.x - xv[i].x, e1 = q.y - xv[i].y, e2 = q.z - xv[i].z, e3 = q.w - xv[i].w;
    sse += e0 * e0 + e1 * e1 + e2 * e2 + e3 * e3;
  }
  red[tid] = sse;
  ib[tid]  = bidx;
  __syncthreads();

  // coalesced cooperative quantized write: each wave writes one row per step
  const size_t obase = OUT_Q_OFF + (size_t)blockIdx.x * (256 * DIM);
  for (int j = 0; j < 64; j++) {
    int e = j * 256 + tid;                 // linear element in this block's 256x64 tile
    out[obase + e] = wn[(size_t)ib[e >> 6] * DIM + (e & 63)];
  }

  // block SSE reduction
  for (int s = 128; s > 0; s >>= 1) {
    if (tid < s) red[tid] += red[tid + s];
    __syncthreads();
  }
  if (tid == 0) block_sse[blockIdx.x] = red[0];
}

__global__ void __launch_bounds__(1024) finalize_kernel(
    const unsigned* __restrict__ counts, const float* __restrict__ block_sse,
    float* __restrict__ out) {
  __shared__ float red[1024];
  const int t = threadIdx.x;

  // perplexity: exp(-sum(avg * log(avg + 1e-10)))
  float cv  = (float)counts[t];
  float avg = cv * (1.0f / (float)NROWS);
  red[t] = avg * logf(avg + 1e-10f);
  __syncthreads();
  for (int s = 512; s > 0; s >>= 1) {
    if (t < s) red[t] += red[t + s];
    __syncthreads();
  }
  const float H = -red[0];   // valid for all threads after final sync
  __syncthreads();

  // loss: 1.25 * mean((q - xn)^2); fl(m + 0.25m) == fl(1.25m)
  red[t] = (t < 256) ? block_sse[t] : 0.f;
  __syncthreads();
  for (int s = 512; s > 0; s >>= 1) {
    if (t < s) red[t] += red[t + s];
    __syncthreads();
  }
  if (t == 0) {
    float mse = red[0] * (1.0f / (float)((size_t)NROWS * DIM));  // /2^22, exact
    out[0] = mse + 0.25f * mse;
    out[OUT_PERP_OFF] = expf(H);
  }
}

extern "C" void kernel_launch(void* const* d_in, const int* in_sizes, int n_in,
                              void* d_out, int out_size, void* d_ws, size_t ws_size,
                              hipStream_t stream) {
  const float* x = (const float*)d_in[0];   // [16,4096,64] fp32
  const float* w = (const float*)d_in[1];   // [1024,64] fp32
  float* out = (float*)d_out;

  unsigned* counts    = (unsigned*)d_ws;
  float*    block_sse = (float*)((char*)d_ws + 4096);
  float*    wn        = (float*)((char*)d_ws + 5120);
  float*    sk        = (float*)((char*)d_ws + 5120 + (size_t)KCODES * DIM * 4);

  // counts + block_sse must be zero every call (ws is poisoned 0xAA)
  hipMemsetAsync(d_ws, 0, 5120, stream);

  normalize_w_kernel<<<KCODES, 64, 0, stream>>>(w, wn, sk);
  vq_main_kernel<<<NROWS / 256, 256, 0, stream>>>(x, wn, sk, out, counts, block_sse);
  finalize_kernel<<<1, 1024, 0, stream>>>(counts, block_sse, out);
}

// Round 2
// 219.414 us; speedup vs baseline: 1.5917x; 1.5917x over previous
//
#include <hip/hip_runtime.h>
#include <hip/hip_bf16.h>
#include <math.h>

// Problem constants (fixed by the reference)
#define NROWS   65536          // 16*4096 flattened rows
#define DIM     64             // embedding dim
#define KCODES  1024           // num embeddings
#define KSPLIT  4              // codebook splits (blockIdx.y)
#define KPER    (KCODES / KSPLIT)

// Output layout (floats), concatenated in reference return order:
//   out[0]                               loss
//   out[1 .. 1+NROWS*DIM-1]              quantized_ste  (== wn[idx] numerically)
//   out[1+NROWS*DIM]                     perplexity
//   out[2+NROWS*DIM .. ]                 encoding_indices (written as float)
#define OUT_Q_OFF    ((size_t)1)
#define OUT_PERP_OFF ((size_t)(1 + (size_t)NROWS * DIM))
#define OUT_IDX_OFF  ((size_t)(2 + (size_t)NROWS * DIM))

// Workspace layout (bytes):
//   [0,      4096)     unsigned counts[1024]       (zeroed each call)
//   [4096,   5120)     float block_sse[256]        (zeroed each call)
//   [5120,   267264)   float wn[65536]             (normalized codebook)
//   [267264, 271360)   float sk[1024]              (sum(wn^2) per code)
//   [271360, 2368512)  float2 pairs[KSPLIT][NROWS] (per-split best dist/idx)

__global__ void __launch_bounds__(64) normalize_w_kernel(
    const float* __restrict__ w, float* __restrict__ wn, float* __restrict__ sk) {
  const int k = blockIdx.x;   // one code per 64-lane wave
  const int d = threadIdx.x;
  float v = w[k * DIM + d];
  float ss = v * v;
  #pragma unroll
  for (int o = 32; o > 0; o >>= 1) ss += __shfl_xor(ss, o, 64);
  const float den = fmaxf(sqrtf(ss), 1e-12f);   // torch/jax F.normalize eps
  const float q = v / den;                      // true division to hug reference rounding
  wn[k * DIM + d] = q;
  float s2 = q * q;
  #pragma unroll
  for (int o = 32; o > 0; o >>= 1) s2 += __shfl_xor(s2, o, 64);
  if (d == 0) sk[k] = s2;
}

// One row per thread; w-operand read with wave-UNIFORM addresses straight from
// global (uniformity analysis -> s_load into SGPRs; worst case L1-hit VMEM).
// No LDS at all in this kernel.
__global__ void __launch_bounds__(256) vq_partial_kernel(
    const float* __restrict__ x, const float* __restrict__ wn,
    const float* __restrict__ sk, float2* __restrict__ pairs) {
  const int tid = threadIdx.x;
  const size_t r = (size_t)blockIdx.x * 256 + tid;   // row
  const int split = blockIdx.y;                      // code range

  // ---- load + L2-normalize this thread's row into registers (64 VGPRs) ----
  float4 xv[16];
  const float4* xrow = (const float4*)(x + r * DIM);
  #pragma unroll
  for (int i = 0; i < 16; i++) xv[i] = xrow[i];
  float ss = 0.f;
  #pragma unroll
  for (int i = 0; i < 16; i++)
    ss += xv[i].x * xv[i].x + xv[i].y * xv[i].y + xv[i].z * xv[i].z + xv[i].w * xv[i].w;
  const float den = fmaxf(sqrtf(ss), 1e-12f);
  #pragma unroll
  for (int i = 0; i < 16; i++) {
    xv[i].x /= den; xv[i].y /= den; xv[i].z /= den; xv[i].w /= den;
  }
  // c = sum(xn^2), kept to mirror reference rounding of (c + sk) - 2*dot
  float c = 0.f;
  #pragma unroll
  for (int i = 0; i < 16; i++)
    c += xv[i].x * xv[i].x + xv[i].y * xv[i].y + xv[i].z * xv[i].z + xv[i].w * xv[i].w;

  float best = INFINITY;
  int bidx = 0;

  const int k0 = split * KPER;
  #pragma unroll 2
  for (int k = k0; k < k0 + KPER; k++) {
    const float* __restrict__ wr = wn + (size_t)k * DIM;  // wave-uniform address
    float d0 = 0.f, d1 = 0.f, d2 = 0.f, d3 = 0.f;
    #pragma unroll
    for (int i = 0; i < 16; i++) {
      const float w0 = wr[4 * i + 0];
      const float w1 = wr[4 * i + 1];
      const float w2 = wr[4 * i + 2];
      const float w3 = wr[4 * i + 3];
      d0 = fmaf(xv[i].x, w0, d0);
      d1 = fmaf(xv[i].y, w1, d1);
      d2 = fmaf(xv[i].z, w2, d2);
      d3 = fmaf(xv[i].w, w3, d3);
    }
    const float dot = (d0 + d1) + (d2 + d3);
    const float dist = (c + sk[k]) - 2.0f * dot;
    if (dist < best) { best = dist; bidx = k; }  // strict <: first-min, matches jnp.argmin
  }

  pairs[(size_t)split * NROWS + r] = make_float2(best, __int_as_float(bidx));
}

// Per-row argmin over the KSPLIT candidates + all bookkeeping.
__global__ void __launch_bounds__(256) vq_combine_kernel(
    const float2* __restrict__ pairs, const float* __restrict__ wn,
    float* __restrict__ out, unsigned* __restrict__ counts,
    float* __restrict__ block_sse) {
  __shared__ float red[256];
  __shared__ int   ib[256];
  const int tid = threadIdx.x;
  const size_t r = (size_t)blockIdx.x * 256 + tid;

  float best = INFINITY;
  int bidx = 0;
  #pragma unroll
  for (int s = 0; s < KSPLIT; s++) {       // ascending split order => ascending idx
    const float2 p = pairs[(size_t)s * NROWS + r];
    const int pi = __float_as_int(p.y);
    if (p.x < best) { best = p.x; bidx = pi; }
  }

  out[OUT_IDX_OFF + r] = (float)bidx;
  atomicAdd(&counts[bidx], 1u);
  red[tid] = best;      // dist == sum((wn[bidx]-xn)^2) to ~1e-6
  ib[tid]  = bidx;
  __syncthreads();

  // coalesced cooperative quantized write (wn rows come from L2/L3, 256 KB)
  const size_t obase = OUT_Q_OFF + (size_t)blockIdx.x * (256 * DIM);
  for (int j = 0; j < 64; j++) {
    const int e = j * 256 + tid;            // linear element in this block's 256x64 tile
    out[obase + e] = wn[(size_t)ib[e >> 6] * DIM + (e & 63)];
  }

  // block SSE reduction
  for (int s = 128; s > 0; s >>= 1) {
    if (tid < s) red[tid] += red[tid + s];
    __syncthreads();
  }
  if (tid == 0) block_sse[blockIdx.x] = red[0];
}

__global__ void __launch_bounds__(1024) finalize_kernel(
    const unsigned* __restrict__ counts, const float* __restrict__ block_sse,
    float* __restrict__ out) {
  __shared__ float red[1024];
  const int t = threadIdx.x;

  // perplexity: exp(-sum(avg * log(avg + 1e-10)))
  float cv  = (float)counts[t];
  float avg = cv * (1.0f / (float)NROWS);
  red[t] = avg * logf(avg + 1e-10f);
  __syncthreads();
  for (int s = 512; s > 0; s >>= 1) {
    if (t < s) red[t] += red[t + s];
    __syncthreads();
  }
  const float H = -red[0];
  __syncthreads();

  // loss: 1.25 * mean((q - xn)^2); fl(m + 0.25m) == fl(1.25m)
  red[t] = (t < 256) ? block_sse[t] : 0.f;
  __syncthreads();
  for (int s = 512; s > 0; s >>= 1) {
    if (t < s) red[t] += red[t + s];
    __syncthreads();
  }
  if (t == 0) {
    float mse = red[0] * (1.0f / (float)((size_t)NROWS * DIM));  // /2^22, exact
    out[0] = mse + 0.25f * mse;
    out[OUT_PERP_OFF] = expf(H);
  }
}

extern "C" void kernel_launch(void* const* d_in, const int* in_sizes, int n_in,
                              void* d_out, int out_size, void* d_ws, size_t ws_size,
                              hipStream_t stream) {
  const float* x = (const float*)d_in[0];   // [16,4096,64] fp32
  const float* w = (const float*)d_in[1];   // [1024,64] fp32
  float* out = (float*)d_out;

  unsigned* counts    = (unsigned*)d_ws;
  float*    block_sse = (float*)((char*)d_ws + 4096);
  float*    wn        = (float*)((char*)d_ws + 5120);
  float*    sk        = (float*)((char*)d_ws + 5120 + (size_t)KCODES * DIM * 4);
  float2*   pairs     = (float2*)((char*)d_ws + 271360);

  // counts + block_sse must be zero every call (ws is poisoned 0xAA)
  hipMemsetAsync(d_ws, 0, 5120, stream);

  normalize_w_kernel<<<KCODES, 64, 0, stream>>>(w, wn, sk);
  vq_partial_kernel<<<dim3(NROWS / 256, KSPLIT), 256, 0, stream>>>(x, wn, sk, pairs);
  vq_combine_kernel<<<NROWS / 256, 256, 0, stream>>>(pairs, wn, out, counts, block_sse);
  finalize_kernel<<<1, 1024, 0, stream>>>(counts, block_sse, out);
}

// Round 3
// 208.293 us; speedup vs baseline: 1.6767x; 1.0534x over previous
//
#include <hip/hip_runtime.h>
#include <hip/hip_bf16.h>
#include <math.h>

// Problem constants (fixed by the reference)
#define NROWS   65536          // 16*4096 flattened rows
#define DIM     64             // embedding dim
#define KCODES  1024           // num embeddings
#define KSPLIT  8              // codebook splits (blockIdx.y) -> 2048 blocks, 32 waves/CU
#define KPER    (KCODES / KSPLIT)

typedef float v2f __attribute__((ext_vector_type(2)));   // -> v_pk_fma_f32 candidates

// Output layout (floats), concatenated in reference return order:
//   out[0]                               loss
//   out[1 .. 1+NROWS*DIM-1]              quantized_ste  (== wn[idx] numerically)
//   out[1+NROWS*DIM]                     perplexity
//   out[2+NROWS*DIM .. ]                 encoding_indices (written as float)
#define OUT_Q_OFF    ((size_t)1)
#define OUT_PERP_OFF ((size_t)(1 + (size_t)NROWS * DIM))
#define OUT_IDX_OFF  ((size_t)(2 + (size_t)NROWS * DIM))

// Workspace layout (bytes):
//   [0,      4096)     unsigned counts[1024]       (zeroed each call)
//   [4096,   5120)     float block_sse[256]        (zeroed each call)
//   [5120,   267264)   float wn[65536]             (normalized codebook)
//   [267264, 271360)   float sk[1024]              (sum(wn^2) per code)
//   [271360, ...)      float2 pairs[KSPLIT][NROWS] (per-split best dist/idx) = 4 MB

__global__ void __launch_bounds__(64) normalize_w_kernel(
    const float* __restrict__ w, float* __restrict__ wn, float* __restrict__ sk) {
  const int k = blockIdx.x;   // one code per 64-lane wave
  const int d = threadIdx.x;
  float v = w[k * DIM + d];
  float ss = v * v;
  #pragma unroll
  for (int o = 32; o > 0; o >>= 1) ss += __shfl_xor(ss, o, 64);
  const float den = fmaxf(sqrtf(ss), 1e-12f);   // torch/jax F.normalize eps
  const float q = v / den;                      // true division to hug reference rounding
  wn[k * DIM + d] = q;
  float s2 = q * q;
  #pragma unroll
  for (int o = 32; o > 0; o >>= 1) s2 += __shfl_xor(s2, o, 64);
  if (d == 0) sk[k] = s2;
}

// One row per thread; w-operand read with wave-UNIFORM addresses (s_load into
// SGPRs). Inner loop in float2 ext-vectors to bait v_pk_fma_f32 (2 FMA/lane).
__global__ void __launch_bounds__(256) vq_partial_kernel(
    const float* __restrict__ x, const float* __restrict__ wn,
    const float* __restrict__ sk, float2* __restrict__ pairs) {
  const int tid = threadIdx.x;
  const size_t r = (size_t)blockIdx.x * 256 + tid;   // row
  const int split = blockIdx.y;                      // code range

  // ---- load + L2-normalize this thread's row into registers (64 VGPRs) ----
  v2f xv[32];
  {
    const float4* xrow = (const float4*)(x + r * DIM);
    #pragma unroll
    for (int i = 0; i < 16; i++) {
      float4 t = xrow[i];
      xv[2 * i]     = (v2f){t.x, t.y};
      xv[2 * i + 1] = (v2f){t.z, t.w};
    }
  }
  float ss = 0.f;
  #pragma unroll
  for (int i = 0; i < 32; i++) ss += xv[i].x * xv[i].x + xv[i].y * xv[i].y;
  const float den = fmaxf(sqrtf(ss), 1e-12f);
  #pragma unroll
  for (int i = 0; i < 32; i++) { xv[i].x /= den; xv[i].y /= den; }
  // c = sum(xn^2), kept to mirror reference rounding of (c + sk) - 2*dot
  float c = 0.f;
  #pragma unroll
  for (int i = 0; i < 32; i++) c += xv[i].x * xv[i].x + xv[i].y * xv[i].y;

  float best = INFINITY;
  int bidx = 0;

  const int k0 = split * KPER;
  #pragma unroll 2
  for (int k = k0; k < k0 + KPER; k++) {
    const v2f* __restrict__ wr = (const v2f*)(wn + (size_t)k * DIM);  // wave-uniform
    v2f a0 = (v2f){0.f, 0.f}, a1 = (v2f){0.f, 0.f};
    v2f a2 = (v2f){0.f, 0.f}, a3 = (v2f){0.f, 0.f};
    #pragma unroll
    for (int i = 0; i < 32; i += 4) {
      a0 = __builtin_elementwise_fma(xv[i + 0], wr[i + 0], a0);
      a1 = __builtin_elementwise_fma(xv[i + 1], wr[i + 1], a1);
      a2 = __builtin_elementwise_fma(xv[i + 2], wr[i + 2], a2);
      a3 = __builtin_elementwise_fma(xv[i + 3], wr[i + 3], a3);
    }
    const v2f a01 = a0 + a1, a23 = a2 + a3;
    const v2f as = a01 + a23;
    const float dot = as.x + as.y;
    const float dist = (c + sk[k]) - 2.0f * dot;
    if (dist < best) { best = dist; bidx = k; }  // strict <: first-min, matches jnp.argmin
  }

  pairs[(size_t)split * NROWS + r] = make_float2(best, __int_as_float(bidx));
}

// Per-row argmin over the KSPLIT candidates + all bookkeeping.
__global__ void __launch_bounds__(256) vq_combine_kernel(
    const float2* __restrict__ pairs, const float* __restrict__ wn,
    float* __restrict__ out, unsigned* __restrict__ counts,
    float* __restrict__ block_sse) {
  __shared__ float red[256];
  __shared__ int   ib[256];
  const int tid = threadIdx.x;
  const size_t r = (size_t)blockIdx.x * 256 + tid;

  float best = INFINITY;
  int bidx = 0;
  #pragma unroll
  for (int s = 0; s < KSPLIT; s++) {       // ascending split order => ascending idx
    const float2 p = pairs[(size_t)s * NROWS + r];
    const int pi = __float_as_int(p.y);
    if (p.x < best) { best = p.x; bidx = pi; }
  }

  out[OUT_IDX_OFF + r] = (float)bidx;
  atomicAdd(&counts[bidx], 1u);
  red[tid] = best;      // dist == sum((wn[bidx]-xn)^2) to ~1e-6
  ib[tid]  = bidx;
  __syncthreads();

  // coalesced cooperative quantized write; per wave-iteration the source row is
  // wave-uniform (e>>6 constant across the 64 lanes) -> broadcast read
  const size_t obase = OUT_Q_OFF + (size_t)blockIdx.x * (256 * DIM);
  for (int j = 0; j < 64; j++) {
    const int e = j * 256 + tid;            // linear element in this block's 256x64 tile
    out[obase + e] = wn[(size_t)ib[e >> 6] * DIM + (e & 63)];
  }

  // block SSE reduction
  for (int s = 128; s > 0; s >>= 1) {
    if (tid < s) red[tid] += red[tid + s];
    __syncthreads();
  }
  if (tid == 0) block_sse[blockIdx.x] = red[0];
}

__global__ void __launch_bounds__(1024) finalize_kernel(
    const unsigned* __restrict__ counts, const float* __restrict__ block_sse,
    float* __restrict__ out) {
  __shared__ float red[1024];
  const int t = threadIdx.x;

  // perplexity: exp(-sum(avg * log(avg + 1e-10)))
  float cv  = (float)counts[t];
  float avg = cv * (1.0f / (float)NROWS);
  red[t] = avg * logf(avg + 1e-10f);
  __syncthreads();
  for (int s = 512; s > 0; s >>= 1) {
    if (t < s) red[t] += red[t + s];
    __syncthreads();
  }
  const float H = -red[0];
  __syncthreads();

  // loss: 1.25 * mean((q - xn)^2); fl(m + 0.25m) == fl(1.25m)
  red[t] = (t < 256) ? block_sse[t] : 0.f;
  __syncthreads();
  for (int s = 512; s > 0; s >>= 1) {
    if (t < s) red[t] += red[t + s];
    __syncthreads();
  }
  if (t == 0) {
    float mse = red[0] * (1.0f / (float)((size_t)NROWS * DIM));  // /2^22, exact
    out[0] = mse + 0.25f * mse;
    out[OUT_PERP_OFF] = expf(H);
  }
}

extern "C" void kernel_launch(void* const* d_in, const int* in_sizes, int n_in,
                              void* d_out, int out_size, void* d_ws, size_t ws_size,
                              hipStream_t stream) {
  const float* x = (const float*)d_in[0];   // [16,4096,64] fp32
  const float* w = (const float*)d_in[1];   // [1024,64] fp32
  float* out = (float*)d_out;

  unsigned* counts    = (unsigned*)d_ws;
  float*    block_sse = (float*)((char*)d_ws + 4096);
  float*    wn        = (float*)((char*)d_ws + 5120);
  float*    sk        = (float*)((char*)d_ws + 5120 + (size_t)KCODES * DIM * 4);
  float2*   pairs     = (float2*)((char*)d_ws + 271360);

  // counts + block_sse must be zero every call (ws is poisoned 0xAA)
  hipMemsetAsync(d_ws, 0, 5120, stream);

  normalize_w_kernel<<<KCODES, 64, 0, stream>>>(w, wn, sk);
  vq_partial_kernel<<<dim3(NROWS / 256, KSPLIT), 256, 0, stream>>>(x, wn, sk, pairs);
  vq_combine_kernel<<<NROWS / 256, 256, 0, stream>>>(pairs, wn, out, counts, block_sse);
  finalize_kernel<<<1, 1024, 0, stream>>>(counts, block_sse, out);
}

// Round 4
// 165.846 us; speedup vs baseline: 2.1059x; 1.2559x over previous
//
#include <hip/hip_runtime.h>
#include <hip/hip_bf16.h>
#include <math.h>

// Problem constants (fixed by the reference)
#define NROWS   65536          // 16*4096 flattened rows
#define DIM     64             // embedding dim
#define KCODES  1024           // num embeddings

typedef short short8 __attribute__((ext_vector_type(8)));   // 8 bf16 = 4 VGPR (MFMA A/B frag)
typedef float f32x4  __attribute__((ext_vector_type(4)));   // MFMA C/D frag

// Output layout (floats), reference return order:
//   out[0] loss | out[1..] quantized (N*D) | perplexity | indices (as float)
#define OUT_Q_OFF    ((size_t)1)
#define OUT_PERP_OFF ((size_t)(1 + (size_t)NROWS * DIM))
#define OUT_IDX_OFF  ((size_t)(2 + (size_t)NROWS * DIM))

// Workspace layout (bytes)
#define WS_COUNTS 0                               // unsigned[1024]   (zeroed)
#define WS_BSSE   4096                            // float[512]       (zeroed)
#define WS_QCOUNT 6144                            // unsigned         (zeroed)
#define WS_WN     8192                            // float wn[1024*64]
#define WS_SK     (WS_WN + KCODES*DIM*4)          // float sk[1024]
#define WS_WNH    (WS_SK + KCODES*4)              // ushort wnh[1024*64]
#define WS_WNL    (WS_WNH + KCODES*DIM*2)         // ushort wnl[1024*64]
#define WS_IDX    (WS_WNL + KCODES*DIM*2)         // unsigned idx[65536]
#define WS_QUEUE  (WS_IDX + NROWS*4)              // unsigned queue[65536]

__device__ __forceinline__ unsigned short bf16_rne(float f) {
  unsigned u = __float_as_uint(f);
  return (unsigned short)((u + 0x7FFFu + ((u >> 16) & 1u)) >> 16);
}
__device__ __forceinline__ float bf16f(unsigned short h) {
  return __uint_as_float(((unsigned)h) << 16);
}

__global__ void __launch_bounds__(64) normalize_w_kernel(
    const float* __restrict__ w, float* __restrict__ wn, float* __restrict__ sk,
    unsigned short* __restrict__ wnh, unsigned short* __restrict__ wnl) {
  const int k = blockIdx.x;   // one code per 64-lane wave
  const int d = threadIdx.x;
  float v = w[k * DIM + d];
  float ss = v * v;
  #pragma unroll
  for (int o = 32; o > 0; o >>= 1) ss += __shfl_xor(ss, o, 64);
  const float den = fmaxf(sqrtf(ss), 1e-12f);
  const float q = v / den;                 // true division: hug reference rounding
  wn[k * DIM + d] = q;
  const unsigned short h = bf16_rne(q);
  wnh[k * DIM + d] = h;
  wnl[k * DIM + d] = bf16_rne(q - bf16f(h));
  float s2 = q * q;
  #pragma unroll
  for (int o = 32; o > 0; o >>= 1) s2 += __shfl_xor(s2, o, 64);
  if (d == 0) sk[k] = s2;
}

// Split-2 bf16 MFMA filter. Block = 256 thr (4 waves), 128 rows.
// Wave w owns rows 32w..32w+31 (2 row-tiles of 16); K-loop: 16 LDS chunks of
// 64 codes. dot ~= xh.wh + xh.wl + xl.wh (err <= ~1.3e-5). Per-lane running
// top-2 as u32 keys: high 22 bits = (dist+4.0) fp32 bits truncated, low 10 =
// code. Fallback iff best/second within <2 quant bins (bin >= 2.4e-4 >> err).
__global__ void __launch_bounds__(256) vq_filter_kernel(
    const float* __restrict__ x, const unsigned short* __restrict__ wnh,
    const unsigned short* __restrict__ wnl, const float* __restrict__ sk,
    unsigned* __restrict__ idx_arr, unsigned* __restrict__ queue,
    unsigned* __restrict__ qcount) {
  __shared__ unsigned AhU[128 * 36];   // 128 rows x 72 shorts (64 + 8 pad)
  __shared__ unsigned AlU[128 * 36];
  __shared__ unsigned BhU[64 * 36];    // 64 codes x 72 shorts
  __shared__ unsigned BlU[64 * 36];
  __shared__ float sklds[64];
  const int tid = threadIdx.x;
  const int lane = tid & 63, wave = tid >> 6;

  // ---- phase 1: threads 0..127 normalize one row each, split to bf16 hi/lo ----
  if (tid < 128) {
    const size_t row = (size_t)blockIdx.x * 128 + tid;
    const float4* xr = (const float4*)(x + row * DIM);
    float4 xv[16];
    float ss = 0.f;
    #pragma unroll
    for (int i = 0; i < 16; i++) {
      xv[i] = xr[i];
      ss += xv[i].x * xv[i].x + xv[i].y * xv[i].y + xv[i].z * xv[i].z + xv[i].w * xv[i].w;
    }
    const float inv = 1.0f / fmaxf(sqrtf(ss), 1e-12f);   // approx xn ok: filter only
    #pragma unroll
    for (int i = 0; i < 16; i++) {
      const float a0 = xv[i].x * inv, a1 = xv[i].y * inv;
      const float a2 = xv[i].z * inv, a3 = xv[i].w * inv;
      const unsigned short h0 = bf16_rne(a0), h1 = bf16_rne(a1);
      const unsigned short h2 = bf16_rne(a2), h3 = bf16_rne(a3);
      const unsigned short l0 = bf16_rne(a0 - bf16f(h0)), l1 = bf16_rne(a1 - bf16f(h1));
      const unsigned short l2 = bf16_rne(a2 - bf16f(h2)), l3 = bf16_rne(a3 - bf16f(h3));
      AhU[tid * 36 + 2 * i]     = (unsigned)h0 | ((unsigned)h1 << 16);
      AhU[tid * 36 + 2 * i + 1] = (unsigned)h2 | ((unsigned)h3 << 16);
      AlU[tid * 36 + 2 * i]     = (unsigned)l0 | ((unsigned)l1 << 16);
      AlU[tid * 36 + 2 * i + 1] = (unsigned)l2 | ((unsigned)l3 << 16);
    }
  }
  __syncthreads();

  // ---- A fragments -> registers (A[m=lane&15][k=(lane>>4)*8+j]) ----
  const short* Ah = (const short*)AhU;
  const short* Al = (const short*)AlU;
  short8 ah[2][2], al[2][2];
  #pragma unroll
  for (int rt = 0; rt < 2; rt++)
    #pragma unroll
    for (int kk = 0; kk < 2; kk++) {
      const int r = wave * 32 + rt * 16 + (lane & 15);
      ah[rt][kk] = *(const short8*)&Ah[r * 72 + kk * 32 + (lane >> 4) * 8];
      al[rt][kk] = *(const short8*)&Al[r * 72 + kk * 32 + (lane >> 4) * 8];
    }

  unsigned k1[8], k2[8];
  #pragma unroll
  for (int s = 0; s < 8; s++) { k1[s] = 0xFFFFFFFFu; k2[s] = 0xFFFFFFFFu; }

  for (int c = 0; c < 16; c++) {   // 16 chunks x 64 codes
    __syncthreads();
    {  // cooperative stage: 64 codes hi+lo (+sk) into LDS
      const int code = tid >> 2, qq = tid & 3;    // 16 shorts per quarter
      const float4* gh = (const float4*)(wnh + (size_t)(c * 64 + code) * DIM + qq * 16);
      const float4* gl = (const float4*)(wnl + (size_t)(c * 64 + code) * DIM + qq * 16);
      float4* dh = (float4*)&BhU[code * 36 + qq * 8];
      float4* dl = (float4*)&BlU[code * 36 + qq * 8];
      dh[0] = gh[0]; dh[1] = gh[1];
      dl[0] = gl[0]; dl[1] = gl[1];
      if (tid < 64) sklds[tid] = sk[c * 64 + tid];
    }
    __syncthreads();
    const short* Bh = (const short*)BhU;
    const short* Bl = (const short*)BlU;
    #pragma unroll
    for (int tt = 0; tt < 4; tt++) {
      const int cb = tt * 16 + (lane & 15);       // code within chunk (B col)
      const float skv = sklds[cb];
      const unsigned codev = (unsigned)(c * 64 + cb);
      const short8 bh0 = *(const short8*)&Bh[cb * 72 + 0 * 32 + (lane >> 4) * 8];
      const short8 bh1 = *(const short8*)&Bh[cb * 72 + 1 * 32 + (lane >> 4) * 8];
      const short8 bl0 = *(const short8*)&Bl[cb * 72 + 0 * 32 + (lane >> 4) * 8];
      const short8 bl1 = *(const short8*)&Bl[cb * 72 + 1 * 32 + (lane >> 4) * 8];
      #pragma unroll
      for (int rt = 0; rt < 2; rt++) {
        f32x4 acc = {0.f, 0.f, 0.f, 0.f};
        acc = __builtin_amdgcn_mfma_f32_16x16x32_bf16(ah[rt][0], bh0, acc, 0, 0, 0);
        acc = __builtin_amdgcn_mfma_f32_16x16x32_bf16(ah[rt][1], bh1, acc, 0, 0, 0);
        acc = __builtin_amdgcn_mfma_f32_16x16x32_bf16(al[rt][0], bh0, acc, 0, 0, 0);
        acc = __builtin_amdgcn_mfma_f32_16x16x32_bf16(al[rt][1], bh1, acc, 0, 0, 0);
        acc = __builtin_amdgcn_mfma_f32_16x16x32_bf16(ah[rt][0], bl0, acc, 0, 0, 0);
        acc = __builtin_amdgcn_mfma_f32_16x16x32_bf16(ah[rt][1], bl1, acc, 0, 0, 0);
        #pragma unroll
        for (int i = 0; i < 4; i++) {   // C layout: col=lane&15(code), row=(lane>>4)*4+i
          const float dist = fmaf(-2.0f, acc[i], skv);   // + c_row dropped: uniform per row
          const unsigned key = (__float_as_uint(dist + 4.0f) & ~1023u) | codev;
          const int s = rt * 4 + i;
          const unsigned mx = (k1[s] > key) ? k1[s] : key;
          k2[s] = (k2[s] < mx) ? k2[s] : mx;
          k1[s] = (k1[s] < key) ? k1[s] : key;
        }
      }
    }
  }

  // ---- per-row top-2 reduce across the 16 lanes of each group ----
  #pragma unroll
  for (int s = 0; s < 8; s++) {
    unsigned a = k1[s], b = k2[s];
    #pragma unroll
    for (int m = 1; m < 16; m <<= 1) {
      const unsigned pa = (unsigned)__shfl_xor((int)a, m, 64);
      const unsigned pb = (unsigned)__shfl_xor((int)b, m, 64);
      const unsigned mx = (a > pa) ? a : pa;
      const unsigned mn2 = (b < pb) ? b : pb;
      b = (mn2 < mx) ? mn2 : mx;
      a = (a < pa) ? a : pa;     // distinct code bits => no exact key ties; min = smaller code
    }
    if ((lane & 15) == 0) {
      const int row_local = wave * 32 + (s >> 2) * 16 + (lane >> 4) * 4 + (s & 3);
      const size_t row = (size_t)blockIdx.x * 128 + row_local;
      idx_arr[row] = a & 1023u;
      if (((b >> 10) - (a >> 10)) < 2u) {   // same/adjacent bin -> exact recheck
        const unsigned qp = atomicAdd(qcount, 1u);
        queue[qp] = (unsigned)row;
      }
    }
  }
}

// Exact fp32 re-scan for queued rows: one wave per row, lane l covers codes
// l, 64+l, ... (summation order replicates the round-3 kernel that passed).
__global__ void __launch_bounds__(256) vq_refine_kernel(
    const float* __restrict__ x, const float* __restrict__ wn,
    const float* __restrict__ sk, const unsigned* __restrict__ queue,
    const unsigned* __restrict__ qcount, unsigned* __restrict__ idx_arr) {
  const int lane = threadIdx.x & 63;
  const unsigned wave_id = blockIdx.x * 4 + (threadIdx.x >> 6);
  const unsigned qn = *qcount;
  for (unsigned qi = wave_id; qi < qn; qi += 256 * 4) {
    const unsigned row = queue[qi];
    const float4* xr = (const float4*)(x + (size_t)row * DIM);
    float4 xv[16];
    float ss = 0.f;
    #pragma unroll
    for (int i = 0; i < 16; i++) {
      xv[i] = xr[i];
      ss += xv[i].x * xv[i].x + xv[i].y * xv[i].y + xv[i].z * xv[i].z + xv[i].w * xv[i].w;
    }
    const float den = fmaxf(sqrtf(ss), 1e-12f);
    #pragma unroll
    for (int i = 0; i < 16; i++) { xv[i].x /= den; xv[i].y /= den; xv[i].z /= den; xv[i].w /= den; }
    float cc = 0.f;
    #pragma unroll
    for (int i = 0; i < 16; i++)
      cc += xv[i].x * xv[i].x + xv[i].y * xv[i].y + xv[i].z * xv[i].z + xv[i].w * xv[i].w;

    float best = INFINITY;
    int bidx = 0x7FFFFFFF;
    for (int j = 0; j < 16; j++) {
      const int k = j * 64 + lane;
      const float4* wr = (const float4*)(wn + (size_t)k * DIM);
      float d0 = 0.f, d1 = 0.f, d2 = 0.f, d3 = 0.f;
      #pragma unroll
      for (int i = 0; i < 16; i++) {
        const float4 wv = wr[i];
        d0 = fmaf(xv[i].x, wv.x, d0);
        d1 = fmaf(xv[i].y, wv.y, d1);
        d2 = fmaf(xv[i].z, wv.z, d2);
        d3 = fmaf(xv[i].w, wv.w, d3);
      }
      const float dot = (d0 + d1) + (d2 + d3);
      const float dist = (cc + sk[k]) - 2.0f * dot;
      if (dist < best) { best = dist; bidx = k; }   // per-lane ascending k
    }
    #pragma unroll
    for (int m = 1; m < 64; m <<= 1) {
      const float pb = __shfl_xor(best, m, 64);
      const int pi = __shfl_xor(bidx, m, 64);
      if (pb < best || (pb == best && pi < bidx)) { best = pb; bidx = pi; }  // first-occurrence
    }
    if (lane == 0) idx_arr[row] = (unsigned)bidx;
  }
}

// Final bookkeeping: idx out, counts, exact SSE, coalesced quantized write.
__global__ void __launch_bounds__(256) vq_output_kernel(
    const float* __restrict__ x, const float* __restrict__ wn,
    const unsigned* __restrict__ idx_arr, float* __restrict__ out,
    unsigned* __restrict__ counts, float* __restrict__ block_sse) {
  __shared__ float red[256];
  __shared__ int ib[128];
  const int tid = threadIdx.x;
  float sse = 0.f;
  if (tid < 128) {
    const size_t row = (size_t)blockIdx.x * 128 + tid;
    const float4* xr = (const float4*)(x + row * DIM);
    float4 xv[16];
    float ss = 0.f;
    #pragma unroll
    for (int i = 0; i < 16; i++) {
      xv[i] = xr[i];
      ss += xv[i].x * xv[i].x + xv[i].y * xv[i].y + xv[i].z * xv[i].z + xv[i].w * xv[i].w;
    }
    const float den = fmaxf(sqrtf(ss), 1e-12f);
    #pragma unroll
    for (int i = 0; i < 16; i++) { xv[i].x /= den; xv[i].y /= den; xv[i].z /= den; xv[i].w /= den; }
    const int idx = (int)idx_arr[row];
    ib[tid] = idx;
    out[OUT_IDX_OFF + row] = (float)idx;
    atomicAdd(&counts[idx], 1u);
    const float4* wr = (const float4*)(wn + (size_t)idx * DIM);
    #pragma unroll
    for (int i = 0; i < 16; i++) {
      const float4 q = wr[i];
      const float e0 = q.x - xv[i].x, e1 = q.y - xv[i].y;
      const float e2 = q.z - xv[i].z, e3 = q.w - xv[i].w;
      sse += e0 * e0 + e1 * e1 + e2 * e2 + e3 * e3;
    }
  }
  red[tid] = sse;
  __syncthreads();

  // quantized write: 128 rows x 64 elems; per wave-iter one wn row, coalesced
  const size_t obase = OUT_Q_OFF + (size_t)blockIdx.x * (128 * DIM);
  for (int j = 0; j < 32; j++) {
    const int e = j * 256 + tid;
    out[obase + e] = wn[(size_t)ib[e >> 6] * DIM + (e & 63)];
  }

  for (int s = 128; s > 0; s >>= 1) {
    if (tid < s) red[tid] += red[tid + s];
    __syncthreads();
  }
  if (tid == 0) block_sse[blockIdx.x] = red[0];
}

__global__ void __launch_bounds__(1024) finalize_kernel(
    const unsigned* __restrict__ counts, const float* __restrict__ block_sse,
    float* __restrict__ out) {
  __shared__ float red[1024];
  const int t = threadIdx.x;

  float cv = (float)counts[t];
  float avg = cv * (1.0f / (float)NROWS);
  red[t] = avg * logf(avg + 1e-10f);
  __syncthreads();
  for (int s = 512; s > 0; s >>= 1) {
    if (t < s) red[t] += red[t + s];
    __syncthreads();
  }
  const float H = -red[0];
  __syncthreads();

  red[t] = (t < 512) ? block_sse[t] : 0.f;
  __syncthreads();
  for (int s = 512; s > 0; s >>= 1) {
    if (t < s) red[t] += red[t + s];
    __syncthreads();
  }
  if (t == 0) {
    float mse = red[0] * (1.0f / (float)((size_t)NROWS * DIM));  // /2^22, exact
    out[0] = mse + 0.25f * mse;                                  // == 1.25*mse in fp32
    out[OUT_PERP_OFF] = expf(H);
  }
}

extern "C" void kernel_launch(void* const* d_in, const int* in_sizes, int n_in,
                              void* d_out, int out_size, void* d_ws, size_t ws_size,
                              hipStream_t stream) {
  const float* x = (const float*)d_in[0];   // [16,4096,64] fp32
  const float* w = (const float*)d_in[1];   // [1024,64] fp32
  float* out = (float*)d_out;

  char* ws = (char*)d_ws;
  unsigned* counts       = (unsigned*)(ws + WS_COUNTS);
  float* block_sse       = (float*)(ws + WS_BSSE);
  unsigned* qcount       = (unsigned*)(ws + WS_QCOUNT);
  float* wn              = (float*)(ws + WS_WN);
  float* sk              = (float*)(ws + WS_SK);
  unsigned short* wnh    = (unsigned short*)(ws + WS_WNH);
  unsigned short* wnl    = (unsigned short*)(ws + WS_WNL);
  unsigned* idx_arr      = (unsigned*)(ws + WS_IDX);
  unsigned* queue        = (unsigned*)(ws + WS_QUEUE);

  // counts + block_sse + qcount zeroed every call (ws is poisoned 0xAA)
  hipMemsetAsync(d_ws, 0, 8192, stream);

  normalize_w_kernel<<<KCODES, 64, 0, stream>>>(w, wn, sk, wnh, wnl);
  vq_filter_kernel<<<NROWS / 128, 256, 0, stream>>>(x, wnh, wnl, sk, idx_arr, queue, qcount);
  vq_refine_kernel<<<256, 256, 0, stream>>>(x, wn, sk, queue, qcount, idx_arr);
  vq_output_kernel<<<NROWS / 128, 256, 0, stream>>>(x, wn, idx_arr, out, counts, block_sse);
  finalize_kernel<<<1, 1024, 0, stream>>>(counts, block_sse, out);
}

// Round 5
// 165.281 us; speedup vs baseline: 2.1131x; 1.0034x over previous
//
#include <hip/hip_runtime.h>
#include <hip/hip_bf16.h>
#include <math.h>

// Problem constants (fixed by the reference)
#define NROWS   65536          // 16*4096 flattened rows
#define DIM     64             // embedding dim
#define KCODES  1024           // num embeddings

typedef short short8 __attribute__((ext_vector_type(8)));   // 8 bf16 = 4 VGPR (MFMA A/B frag)
typedef float f32x4  __attribute__((ext_vector_type(4)));   // MFMA C/D frag

// Output layout (floats), reference return order:
//   out[0] loss | out[1..] quantized (N*D) | perplexity | indices (as float)
#define OUT_Q_OFF    ((size_t)1)
#define OUT_PERP_OFF ((size_t)(1 + (size_t)NROWS * DIM))
#define OUT_IDX_OFF  ((size_t)(2 + (size_t)NROWS * DIM))

// Workspace layout (bytes); [0,8192) zeroed every call
#define WS_COUNTS 0                         // unsigned[1024]
#define WS_BSSE   4096                      // float[512]
#define WS_QCOUNT 6144                      // unsigned
#define WS_SSEC   6148                      // float (SSE correction accumulator)
#define WS_WN     8192                      // float wn[1024*64]
#define WS_SK     (WS_WN + KCODES*DIM*4)    // float sk[1024]
#define WS_WNH    (WS_SK + KCODES*4)        // ushort wnh[1024*64]
#define WS_WNL    (WS_WNH + KCODES*DIM*2)   // ushort wnl[1024*64]
#define WS_QUEUE  (WS_WNL + KCODES*DIM*2)   // unsigned queue[65536]
#define WS_QSSE   (WS_QUEUE + NROWS*4)      // float qsse[65536]

__device__ __forceinline__ unsigned short bf16_rne(float f) {
  unsigned u = __float_as_uint(f);
  return (unsigned short)((u + 0x7FFFu + ((u >> 16) & 1u)) >> 16);
}
__device__ __forceinline__ float bf16f(unsigned short h) {
  return __uint_as_float(((unsigned)h) << 16);
}

__global__ void __launch_bounds__(64) normalize_w_kernel(
    const float* __restrict__ w, float* __restrict__ wn, float* __restrict__ sk,
    unsigned short* __restrict__ wnh, unsigned short* __restrict__ wnl) {
  const int k = blockIdx.x;   // one code per 64-lane wave
  const int d = threadIdx.x;
  float v = w[k * DIM + d];
  float ss = v * v;
  #pragma unroll
  for (int o = 32; o > 0; o >>= 1) ss += __shfl_xor(ss, o, 64);
  const float den = fmaxf(sqrtf(ss), 1e-12f);
  const float q = v / den;                 // true division: hug reference rounding
  wn[k * DIM + d] = q;
  const unsigned short h = bf16_rne(q);
  wnh[k * DIM + d] = h;
  wnl[k * DIM + d] = bf16_rne(q - bf16f(h));
  float s2 = q * q;
  #pragma unroll
  for (int o = 32; o > 0; o >>= 1) s2 += __shfl_xor(s2, o, 64);
  if (d == 0) sk[k] = s2;
}

// Fused split-2 bf16 MFMA filter + ALL bookkeeping.
// Block = 256 thr (4 waves) = 128 rows. LDS union: A-frag region (36 KB) is
// dead after frag loads -> reused as double-buffered B region (2 x 18 KB).
// K-loop: 16 chunks x 64 codes, 1 barrier/chunk, staging overlaps compute.
// Keys: high 22 bits of fp32(dist_nc+4), low 10 = code (dist_nc = sk-2dot;
// row-uniform c dropped: argmin/gap invariant). Top-2 via med3+umin.
// Fallback iff best/second within <2 quant bins (bin 4.88e-4 >> err 1.5e-5).
__global__ void __launch_bounds__(256, 4) vq_filter_kernel(
    const float* __restrict__ x, const unsigned short* __restrict__ wnh,
    const unsigned short* __restrict__ wnl, const float* __restrict__ sk,
    const float* __restrict__ wn, float* __restrict__ out,
    unsigned* __restrict__ counts, float* __restrict__ block_sse,
    unsigned* __restrict__ queue, float* __restrict__ qsse,
    unsigned* __restrict__ qcount) {
  // AB union: phase A: Ah=[0,4608) Al=[4608,9216) u32 (128 rows x 36 u32)
  //           phase B: buf b at b*4608: Bh=[+0,+2304) Bl=[+2304,+4608)
  __shared__ unsigned AB[9216];
  __shared__ float skb[2][64];     // sk + 4.0 per staged chunk
  __shared__ float c_arr[128];     // exact-ish ||xn||^2 per row
  __shared__ float rowsse[128];    // per-row approx SSE -> block reduce
  __shared__ int   ib[128];        // per-row provisional idx
  const int tid = threadIdx.x;
  const int lane = tid & 63, wave = tid >> 6;

  // ---- phase 1: threads 0..127 normalize one row each, split to bf16 hi/lo ----
  if (tid < 128) {
    const size_t row = (size_t)blockIdx.x * 128 + tid;
    const float4* xr = (const float4*)(x + row * DIM);
    float4 xv[16];
    float ss = 0.f;
    #pragma unroll
    for (int i = 0; i < 16; i++) {
      xv[i] = xr[i];
      ss += xv[i].x * xv[i].x + xv[i].y * xv[i].y + xv[i].z * xv[i].z + xv[i].w * xv[i].w;
    }
    const float inv = 1.0f / fmaxf(sqrtf(ss), 1e-12f);   // mul-normalize: err ~1e-7 << margin
    float c = 0.f;
    #pragma unroll
    for (int i = 0; i < 16; i++) {
      const float a0 = xv[i].x * inv, a1 = xv[i].y * inv;
      const float a2 = xv[i].z * inv, a3 = xv[i].w * inv;
      c += a0 * a0 + a1 * a1 + a2 * a2 + a3 * a3;
      const unsigned short h0 = bf16_rne(a0), h1 = bf16_rne(a1);
      const unsigned short h2 = bf16_rne(a2), h3 = bf16_rne(a3);
      const unsigned short l0 = bf16_rne(a0 - bf16f(h0)), l1 = bf16_rne(a1 - bf16f(h1));
      const unsigned short l2 = bf16_rne(a2 - bf16f(h2)), l3 = bf16_rne(a3 - bf16f(h3));
      AB[tid * 36 + 2 * i]            = (unsigned)h0 | ((unsigned)h1 << 16);
      AB[tid * 36 + 2 * i + 1]        = (unsigned)h2 | ((unsigned)h3 << 16);
      AB[4608 + tid * 36 + 2 * i]     = (unsigned)l0 | ((unsigned)l1 << 16);
      AB[4608 + tid * 36 + 2 * i + 1] = (unsigned)l2 | ((unsigned)l3 << 16);
    }
    c_arr[tid] = c;
  }
  __syncthreads();

  // ---- A fragments -> registers (A[m=lane&15][k=(lane>>4)*8+j]) ----
  short8 ah[2][2], al[2][2];
  #pragma unroll
  for (int rt = 0; rt < 2; rt++)
    #pragma unroll
    for (int kk = 0; kk < 2; kk++) {
      const int r = wave * 32 + rt * 16 + (lane & 15);
      ah[rt][kk] = *(const short8*)&AB[r * 36 + kk * 16 + (lane >> 4) * 4];
      al[rt][kk] = *(const short8*)&AB[4608 + r * 36 + kk * 16 + (lane >> 4) * 4];
    }
  __syncthreads();   // A region now dead -> becomes B double-buffer

  unsigned k1[8], k2[8];
  #pragma unroll
  for (int s = 0; s < 8; s++) { k1[s] = 0xFFFFFFFFu; k2[s] = 0xFFFFFFFFu; }

  // stage chunk 0 into buf 0
  {
    const int code = tid >> 2, q = tid & 3;
    const float4* gh = (const float4*)(wnh + (size_t)code * DIM + q * 16);
    const float4* gl = (const float4*)(wnl + (size_t)code * DIM + q * 16);
    float4* dh = (float4*)&AB[code * 36 + q * 8];
    float4* dl = (float4*)&AB[2304 + code * 36 + q * 8];
    dh[0] = gh[0]; dh[1] = gh[1];
    dl[0] = gl[0]; dl[1] = gl[1];
    if (tid < 64) skb[0][tid] = sk[tid] + 4.0f;
  }

  #pragma unroll 2
  for (int c = 0; c < 16; c++) {
    const int b = c & 1;
    __syncthreads();   // buf b fully staged; buf b^1 free to overwrite
    if (c < 15) {      // stage next chunk (loads fly during compute below)
      const int nb = b ^ 1;
      const int code = tid >> 2, q = tid & 3;
      const float4* gh = (const float4*)(wnh + (size_t)((c + 1) * 64 + code) * DIM + q * 16);
      const float4* gl = (const float4*)(wnl + (size_t)((c + 1) * 64 + code) * DIM + q * 16);
      float4* dh = (float4*)&AB[nb * 4608 + code * 36 + q * 8];
      float4* dl = (float4*)&AB[nb * 4608 + 2304 + code * 36 + q * 8];
      dh[0] = gh[0]; dh[1] = gh[1];
      dl[0] = gl[0]; dl[1] = gl[1];
      if (tid < 64) skb[nb][tid] = sk[(c + 1) * 64 + tid] + 4.0f;
    }
    #pragma unroll
    for (int tt = 0; tt < 4; tt++) {
      const int cb = tt * 16 + (lane & 15);       // code within chunk (B col)
      const float skv4 = skb[b][cb];
      const unsigned codev = (unsigned)(c * 64 + cb);
      const short8 bh0 = *(const short8*)&AB[b * 4608 + cb * 36 + 0 * 16 + (lane >> 4) * 4];
      const short8 bh1 = *(const short8*)&AB[b * 4608 + cb * 36 + 1 * 16 + (lane >> 4) * 4];
      const short8 bl0 = *(const short8*)&AB[b * 4608 + 2304 + cb * 36 + 0 * 16 + (lane >> 4) * 4];
      const short8 bl1 = *(const short8*)&AB[b * 4608 + 2304 + cb * 36 + 1 * 16 + (lane >> 4) * 4];
      #pragma unroll
      for (int rt = 0; rt < 2; rt++) {
        f32x4 acc = {0.f, 0.f, 0.f, 0.f};
        acc = __builtin_amdgcn_mfma_f32_16x16x32_bf16(ah[rt][0], bh0, acc, 0, 0, 0);
        acc = __builtin_amdgcn_mfma_f32_16x16x32_bf16(ah[rt][1], bh1, acc, 0, 0, 0);
        acc = __builtin_amdgcn_mfma_f32_16x16x32_bf16(al[rt][0], bh0, acc, 0, 0, 0);
        acc = __builtin_amdgcn_mfma_f32_16x16x32_bf16(al[rt][1], bh1, acc, 0, 0, 0);
        acc = __builtin_amdgcn_mfma_f32_16x16x32_bf16(ah[rt][0], bl0, acc, 0, 0, 0);
        acc = __builtin_amdgcn_mfma_f32_16x16x32_bf16(ah[rt][1], bl1, acc, 0, 0, 0);
        #pragma unroll
        for (int i = 0; i < 4; i++) {   // C layout: col=lane&15(code), row=(lane>>4)*4+i
          const float dist4 = fmaf(-2.0f, acc[i], skv4);              // sk+4-2dot
          const unsigned key = (__float_as_uint(dist4) & 0xFFFFFC00u) | codev;  // v_and_or_b32
          const int s = rt * 4 + i;
          unsigned m;   // med3(k1,k2,key) == new 2nd-best given k1<=k2
          asm("v_med3_u32 %0, %1, %2, %3" : "=v"(m) : "v"(k1[s]), "v"(k2[s]), "v"(key));
          k2[s] = m;
          k1[s] = (key < k1[s]) ? key : k1[s];
        }
      }
    }
  }

  // ---- per-row top-2 reduce across the 16 lanes of each group + bookkeeping ----
  #pragma unroll
  for (int s = 0; s < 8; s++) {
    unsigned a = k1[s], bb = k2[s];
    #pragma unroll
    for (int m = 1; m < 16; m <<= 1) {
      const unsigned pa = (unsigned)__shfl_xor((int)a, m, 64);
      const unsigned pb = (unsigned)__shfl_xor((int)bb, m, 64);
      const unsigned mx = (a > pa) ? a : pa;
      const unsigned mn2 = (bb < pb) ? bb : pb;
      bb = (mn2 < mx) ? mn2 : mx;
      a = (a < pa) ? a : pa;   // distinct code bits => strict order; min = smaller code
    }
    if ((lane & 15) == 0) {
      const int row_local = wave * 32 + (s >> 2) * 16 + (lane >> 4) * 4 + (s & 3);
      const size_t row = (size_t)blockIdx.x * 128 + row_local;
      const int idx = (int)(a & 1023u);
      ib[row_local] = idx;
      out[OUT_IDX_OFF + row] = (float)idx;
      atomicAdd(&counts[idx], 1u);
      // approx SSE: quantized dist (+half-bin recenter) + row c
      const float dq = __uint_as_float(a & 0xFFFFFC00u) - 4.0f + c_arr[row_local]
                       + 2.44140625e-4f;
      rowsse[row_local] = dq;
      if (((bb >> 10) - (a >> 10)) < 2u) {   // same/adjacent bin -> exact recheck
        const unsigned qp = atomicAdd(qcount, 1u);
        queue[qp] = (unsigned)row;
        qsse[qp] = dq;
      }
    }
  }
  __syncthreads();

  // ---- quantized write: 128 rows x 64 elems; per wave-iter one wn row (broadcast) ----
  const size_t obase = OUT_Q_OFF + (size_t)blockIdx.x * (128 * DIM);
  for (int j = 0; j < 32; j++) {
    const int e = j * 256 + tid;           // e>>6 wave-uniform
    out[obase + e] = wn[(size_t)ib[e >> 6] * DIM + (e & 63)];
  }

  // ---- block SSE reduction (approx; refine adds exact corrections) ----
  for (int s = 64; s > 0; s >>= 1) {
    if (tid < s) rowsse[tid] += rowsse[tid + s];
    __syncthreads();
  }
  if (tid == 0) block_sse[blockIdx.x] = rowsse[0];
}

// Exact fp32 re-scan for queued rows: one wave per row; fixes idx/counts/
// quantized row when the pick changes, and accumulates exact-SSE correction.
__global__ void __launch_bounds__(256) vq_refine_kernel(
    const float* __restrict__ x, const float* __restrict__ wn,
    const float* __restrict__ sk, const unsigned* __restrict__ queue,
    const float* __restrict__ qsse, const unsigned* __restrict__ qcount,
    float* __restrict__ out, unsigned* __restrict__ counts,
    float* __restrict__ sse_corr) {
  const int lane = threadIdx.x & 63;
  const unsigned wave_id = blockIdx.x * 4 + (threadIdx.x >> 6);
  const unsigned qn = *qcount;
  for (unsigned qi = wave_id; qi < qn; qi += 256 * 4) {
    const unsigned row = queue[qi];
    const float4* xr = (const float4*)(x + (size_t)row * DIM);
    float4 xv[16];
    float ss = 0.f;
    #pragma unroll
    for (int i = 0; i < 16; i++) {
      xv[i] = xr[i];
      ss += xv[i].x * xv[i].x + xv[i].y * xv[i].y + xv[i].z * xv[i].z + xv[i].w * xv[i].w;
    }
    const float den = fmaxf(sqrtf(ss), 1e-12f);
    #pragma unroll
    for (int i = 0; i < 16; i++) { xv[i].x /= den; xv[i].y /= den; xv[i].z /= den; xv[i].w /= den; }
    float cc = 0.f;
    #pragma unroll
    for (int i = 0; i < 16; i++)
      cc += xv[i].x * xv[i].x + xv[i].y * xv[i].y + xv[i].z * xv[i].z + xv[i].w * xv[i].w;

    float best = INFINITY;
    int bidx = 0x7FFFFFFF;
    for (int j = 0; j < 16; j++) {
      const int k = j * 64 + lane;
      const float4* wr = (const float4*)(wn + (size_t)k * DIM);
      float d0 = 0.f, d1 = 0.f, d2 = 0.f, d3 = 0.f;
      #pragma unroll
      for (int i = 0; i < 16; i++) {
        const float4 wv = wr[i];
        d0 = fmaf(xv[i].x, wv.x, d0);
        d1 = fmaf(xv[i].y, wv.y, d1);
        d2 = fmaf(xv[i].z, wv.z, d2);
        d3 = fmaf(xv[i].w, wv.w, d3);
      }
      const float dot = (d0 + d1) + (d2 + d3);
      const float dist = (cc + sk[k]) - 2.0f * dot;
      if (dist < best) { best = dist; bidx = k; }   // per-lane ascending k
    }
    #pragma unroll
    for (int m = 1; m < 64; m <<= 1) {
      const float pb = __shfl_xor(best, m, 64);
      const int pi = __shfl_xor(bidx, m, 64);
      if (pb < best || (pb == best && pi < bidx)) { best = pb; bidx = pi; }  // first-occurrence
    }
    const int oldidx = (int)out[OUT_IDX_OFF + row];
    if (bidx != oldidx) {
      if (lane == 0) {
        out[OUT_IDX_OFF + row] = (float)bidx;
        atomicAdd(&counts[bidx], 1u);
        atomicAdd(&counts[oldidx], 0xFFFFFFFFu);   // -1 (wraps; final count >= 0)
      }
      out[OUT_Q_OFF + (size_t)row * DIM + lane] = wn[(size_t)bidx * DIM + lane];
    }
    if (lane == 0) atomicAdd(sse_corr, best - qsse[qi]);
  }
}

__global__ void __launch_bounds__(1024) finalize_kernel(
    const unsigned* __restrict__ counts, const float* __restrict__ block_sse,
    const float* __restrict__ sse_corr, float* __restrict__ out) {
  __shared__ float red[1024];
  const int t = threadIdx.x;

  float cv = (float)counts[t];
  float avg = cv * (1.0f / (float)NROWS);
  red[t] = avg * logf(avg + 1e-10f);
  __syncthreads();
  for (int s = 512; s > 0; s >>= 1) {
    if (t < s) red[t] += red[t + s];
    __syncthreads();
  }
  const float H = -red[0];
  __syncthreads();

  red[t] = (t < 512) ? block_sse[t] : 0.f;
  __syncthreads();
  for (int s = 512; s > 0; s >>= 1) {
    if (t < s) red[t] += red[t + s];
    __syncthreads();
  }
  if (t == 0) {
    float mse = (red[0] + *sse_corr) * (1.0f / (float)((size_t)NROWS * DIM));
    out[0] = mse + 0.25f * mse;                     // == 1.25*mse in fp32
    out[OUT_PERP_OFF] = expf(H);
  }
}

extern "C" void kernel_launch(void* const* d_in, const int* in_sizes, int n_in,
                              void* d_out, int out_size, void* d_ws, size_t ws_size,
                              hipStream_t stream) {
  const float* x = (const float*)d_in[0];   // [16,4096,64] fp32
  const float* w = (const float*)d_in[1];   // [1024,64] fp32
  float* out = (float*)d_out;

  char* ws = (char*)d_ws;
  unsigned* counts    = (unsigned*)(ws + WS_COUNTS);
  float* block_sse    = (float*)(ws + WS_BSSE);
  unsigned* qcount    = (unsigned*)(ws + WS_QCOUNT);
  float* sse_corr     = (float*)(ws + WS_SSEC);
  float* wn           = (float*)(ws + WS_WN);
  float* sk           = (float*)(ws + WS_SK);
  unsigned short* wnh = (unsigned short*)(ws + WS_WNH);
  unsigned short* wnl = (unsigned short*)(ws + WS_WNL);
  unsigned* queue     = (unsigned*)(ws + WS_QUEUE);
  float* qsse         = (float*)(ws + WS_QSSE);

  // counts + block_sse + qcount + sse_corr zeroed every call (ws poisoned 0xAA)
  hipMemsetAsync(d_ws, 0, 8192, stream);

  normalize_w_kernel<<<KCODES, 64, 0, stream>>>(w, wn, sk, wnh, wnl);
  vq_filter_kernel<<<NROWS / 128, 256, 0, stream>>>(
      x, wnh, wnl, sk, wn, out, counts, block_sse, queue, qsse, qcount);
  vq_refine_kernel<<<256, 256, 0, stream>>>(
      x, wn, sk, queue, qsse, qcount, out, counts, sse_corr);
  finalize_kernel<<<1, 1024, 0, stream>>>(counts, block_sse, sse_corr, out);
}